// Round 1
// baseline (2163.974 us; speedup 1.0000x reference)
//
#include <hip/hip_runtime.h>
#include <math.h>

#define CIN  96
#define COUT 384
#define HH   56
#define WW   56
#define BB   32

// prep: wt[(ci*9 + kh*3 + kw)*384 + co] = (double)w * |(double)w|   (exact fp64 product)
__global__ void prep_weights(const float* __restrict__ w, double* __restrict__ wt) {
    int idx = blockIdx.x * blockDim.x + threadIdx.x;
    if (idx >= COUT * CIN * 9) return;
    int co = idx / (CIN * 9);
    int r  = idx - co * (CIN * 9);      // ci*9 + kh*3 + kw
    double d = (double)w[idx];
    wt[(size_t)r * COUT + co] = d * fabs(d);
}

// Block: (whalf, h, b). 256 threads: lane cg=tid&63 owns co = cg*6..cg*6+5,
// wg=tid>>6 owns w = whalf*28 + wg*7 .. +6.  All 384 co live in one block so
// argmax is done on fp64 accumulators (no fp32-rounding tie hazard).
template <bool WS>
__global__ __launch_bounds__(256, 2)
void conv_wta(const float* __restrict__ x, const double* __restrict__ wt,
              const float* __restrict__ wraw, float* __restrict__ out) {
    const int whalf = blockIdx.x;        // 0..1
    const int h     = blockIdx.y;        // 0..55
    const int b     = blockIdx.z;        // 0..31
    const int tid   = threadIdx.x;
    const int cg    = tid & 63;
    const int wg    = tid >> 6;          // 0..3
    const int co0   = cg * 6;
    const int wbase = whalf * 28 + wg * 7;

    __shared__ float xs[32 * 3 * 30];    // [ci][row][col], col = global_w - (whalf*28 - 1)

    double acc[6][7];
    #pragma unroll
    for (int c = 0; c < 6; ++c)
        #pragma unroll
        for (int i = 0; i < 7; ++i) acc[c][i] = 0.0;

    for (int chunk = 0; chunk < 3; ++chunk) {
        const int ci0 = chunk * 32;
        __syncthreads();
        for (int idx = tid; idx < 32 * 3 * 30; idx += 256) {
            int ci  = idx / 90;
            int rem = idx - ci * 90;
            int r   = rem / 30;
            int c   = rem - r * 30;
            int gh  = h + r - 1;
            int gw  = whalf * 28 - 1 + c;
            float v = 0.0f;
            if ((unsigned)gh < 56u && (unsigned)gw < 56u)
                v = x[(((size_t)b * CIN + (ci0 + ci)) * HH + gh) * WW + gw];
            xs[idx] = v;
        }
        __syncthreads();

        for (int ci = 0; ci < 32; ++ci) {
            const int gci = ci0 + ci;
            #pragma unroll
            for (int kh = 0; kh < 3; ++kh) {
                double xd[9];
                #pragma unroll
                for (int j = 0; j < 9; ++j)
                    xd[j] = (double)xs[(ci * 3 + kh) * 30 + wg * 7 + j];
                #pragma unroll
                for (int kw = 0; kw < 3; ++kw) {
                    double wd[6];
                    if constexpr (WS) {
                        const double* p = wt + (size_t)((gci * 3 + kh) * 3 + kw) * COUT + co0;
                        #pragma unroll
                        for (int c = 0; c < 6; ++c) wd[c] = p[c];
                    } else {
                        #pragma unroll
                        for (int c = 0; c < 6; ++c) {
                            double d = (double)wraw[(size_t)(co0 + c) * (CIN * 9) + gci * 9 + kh * 3 + kw];
                            wd[c] = d * fabs(d);
                        }
                    }
                    #pragma unroll
                    for (int c = 0; c < 6; ++c)
                        #pragma unroll
                        for (int i = 0; i < 7; ++i)
                            acc[c][i] = fma(wd[c], xd[i + kw], acc[c][i]);
                }
            }
        }
    }

    // argmax over all 384 co per w (fp64, first-index tie-break == np.argmax)
    const size_t wta_off = (size_t)BB * COUT * HH * WW;
    #pragma unroll
    for (int i = 0; i < 7; ++i) {
        double best = acc[0][i];
        int bco = co0;
        #pragma unroll
        for (int c = 1; c < 6; ++c)
            if (acc[c][i] > best) { best = acc[c][i]; bco = co0 + c; }
        #pragma unroll
        for (int off = 32; off > 0; off >>= 1) {
            double ov = __shfl_xor(best, off, 64);
            int    oc = __shfl_xor(bco,  off, 64);
            if (ov > best || (ov == best && oc < bco)) { best = ov; bco = oc; }
        }
        const int w = wbase + i;
        #pragma unroll
        for (int c = 0; c < 6; ++c) {
            size_t o = (((size_t)b * COUT + (co0 + c)) * HH + h) * WW + w;
            out[o] = (float)acc[c][i];
            out[wta_off + o] = (co0 + c == bco) ? 1.0f : 0.0f;
        }
    }
}

extern "C" void kernel_launch(void* const* d_in, const int* in_sizes, int n_in,
                              void* d_out, int out_size, void* d_ws, size_t ws_size,
                              hipStream_t stream) {
    (void)in_sizes; (void)n_in; (void)out_size;
    const float* x = (const float*)d_in[0];
    const float* w = (const float*)d_in[1];
    float* out = (float*)d_out;

    const size_t need = (size_t)COUT * CIN * 9 * sizeof(double);
    dim3 grid(2, 56, 32);
    if (ws_size >= need) {
        double* wt = (double*)d_ws;
        prep_weights<<<(COUT * CIN * 9 + 255) / 256, 256, 0, stream>>>(w, wt);
        conv_wta<true><<<grid, 256, 0, stream>>>(x, wt, w, out);
    } else {
        conv_wta<false><<<grid, 256, 0, stream>>>(x, nullptr, w, out);
    }
}